// Round 1
// baseline (199.296 us; speedup 1.0000x reference)
//
#include <hip/hip_runtime.h>
#include <hip/hip_bf16.h>

// Problem: B=32, D=128, H=256, O=10.
// Closed-form differential geometry:
//   s = 1 - tanh(W1^T x + b1)^2, u = -2 z s, M = W2 W2^T, P = W1^T W1,
//   T = M diag(s) W1^T, R = P diag(s) M, Q = T T^T
//   F^2 = 2 sum_{hh'} u_h u_h' [ P^2 o Q + P o R o R^T ]
//   a_i = -(sum_g s_g W1[i,g] m_g) / ((F+1e-6)(||v||+1e-6)),  m = M (u o w^2), w = W1^T v
// Output rows 0..31 = dev_velocity (passthrough), rows 32..63 = a - 0.1*deviation.

#define NB 32
#define DD 128
#define HH 256

// workspace float offsets
#define OW1   0         // 32768  f32 W1 (D x H, row-major d*H+h)
#define OW2   32768     // 2560   f32 W2 (H x O)
#define OB1   35328     // 256    f32 b1
#define OP    35584     // 65536  P
#define OM    101120    // 65536  M
#define OS    166656    // 32x256 s
#define OU    174848    // 32x256 u
#define OAUN  183040    // 32x128 a_un
#define OVN   187136    // 32     ||v||
#define OF2   187168    // 32x16  F^2 partials
#define OFLAG 187700    // int flag (bf16 mode?)
#define OT    187712    // 32x256x128 T  (ends at 1236288 floats ~ 4.95 MB)

__device__ __forceinline__ float ldin(const void* p, int i, int bf) {
  if (bf) return __bfloat162float(((const __hip_bfloat16*)p)[i]);
  return ((const float*)p)[i];
}
__device__ __forceinline__ void stout(void* p, int i, float v, int bf) {
  if (bf) ((__hip_bfloat16*)p)[i] = __float2bfloat16(v);
  else    ((float*)p)[i] = v;
}

// Detect whether float tensors were stored as bf16. Viewing an fp32 buffer as
// bf16 makes ~half the elements mantissa-garbage with random exponents -> huge.
__global__ void k_sniff(const void* sb, int* flag) {
  __shared__ int bad;
  if (threadIdx.x == 0) bad = 0;
  __syncthreads();
  const __hip_bfloat16* p = (const __hip_bfloat16*)sb;
  int lbad = 0;
  for (int i = threadIdx.x; i < 2 * NB * DD; i += 256) {
    float v = __bfloat162float(p[i]);
    if (!(fabsf(v) < 1000.0f)) lbad = 1;   // catches huge, Inf, NaN
  }
  if (lbad) atomicOr(&bad, 1);
  __syncthreads();
  if (threadIdx.x == 0) *flag = (bad == 0) ? 1 : 0;
}

__global__ void k_convert(const void* W1, const void* W2, const void* b1,
                          float* ws, const int* flag) {
  int bf = *flag;
  int i = blockIdx.x * 256 + threadIdx.x;
  if (i < 32768)       ws[OW1 + i] = ldin(W1, i, bf);
  else if (i < 35328)  ws[OW2 + (i - 32768)] = ldin(W2, i - 32768, bf);
  else if (i < 35584)  ws[OB1 + (i - 35328)] = ldin(b1, i - 35328, bf);
}

// P[h,g] = sum_d W1[d,h] W1[d,g];  M[h,g] = sum_o W2[h,o] W2[g,o]
__global__ __launch_bounds__(256) void k_pm(float* ws) {
  __shared__ float w2s[2560];
  __shared__ float colh[128];
  int h = blockIdx.x, t = threadIdx.x;
  for (int i = t; i < 2560; i += 256) w2s[i] = ws[OW2 + i];
  if (t < 128) colh[t] = ws[OW1 + t * 256 + h];
  __syncthreads();
  float pacc = 0.f;
  for (int d = 0; d < 128; ++d) pacc += colh[d] * ws[OW1 + d * 256 + t];
  float macc = 0.f;
  #pragma unroll
  for (int o = 0; o < 10; ++o) macc += w2s[h * 10 + o] * w2s[t * 10 + o];
  ws[OP + h * 256 + t] = pacc;
  ws[OM + h * 256 + t] = macc;
}

// per-batch: s, u, ||v||, a_un
__global__ __launch_bounds__(256) void k_batch(const void* tin, const void* sbin,
                                               const void* x0in, const void* x1in,
                                               float* ws, const int* flag) {
  int bf = *flag;
  int b = blockIdx.x, t = threadIdx.x;
  __shared__ float xs[128], vs[128], tmp[256], sm[256];
  float tt = ldin(tin, 0, bf);
  float window = 4.f * tt * (1.f - tt);
  if (t < 128) {
    float dev = ldin(sbin, b * 128 + t, bf);
    float v   = ldin(sbin, (NB + b) * 128 + t, bf);
    float x0v = ldin(x0in, b * 128 + t, bf);
    float x1v = ldin(x1in, b * 128 + t, bf);
    xs[t] = x0v + tt * (x1v - x0v) + window * dev;
    vs[t] = v;
    tmp[t] = v * v;
  }
  __syncthreads();
  if (t == 0) {
    float sum = 0.f;
    for (int i = 0; i < 128; ++i) sum += tmp[i];
    ws[OVN + b] = sqrtf(sum);
  }
  float hacc = ws[OB1 + t], wacc = 0.f;
  for (int d = 0; d < 128; ++d) {
    float w1 = ws[OW1 + d * 256 + t];   // coalesced over t
    hacc += w1 * xs[d];
    wacc += w1 * vs[d];
  }
  float z  = tanhf(hacc);
  float sg = 1.f - z * z;
  float ug = -2.f * z * sg;
  ws[OS + b * 256 + t] = sg;
  ws[OU + b * 256 + t] = ug;
  __syncthreads();                 // thread0 done with tmp (v^2)
  tmp[t] = ug * wacc * wacc;       // c_h
  __syncthreads();
  float mg = 0.f;
  for (int hh = 0; hh < 256; ++hh) mg += ws[OM + hh * 256 + t] * tmp[hh]; // coalesced
  sm[t] = sg * mg;
  __syncthreads();
  if (t < 128) {
    float a = 0.f;
    for (int g = 0; g < 256; ++g) a += ws[OW1 + t * 256 + g] * sm[g];
    ws[OAUN + b * 128 + t] = a;
  }
}

// T[b][h][j] = sum_g M[h,g] s_g W1[j,g]
__global__ __launch_bounds__(256) void k_T(float* ws) {
  int bid = blockIdx.x;
  int b = bid >> 3, h0 = (bid & 7) * 32;
  int t = threadIdx.x;
  __shared__ float Ms[32][256];
  float sgt = ws[OS + b * 256 + t];
  for (int k = 0; k < 32; ++k)
    Ms[k][t] = ws[OM + (h0 + k) * 256 + t] * sgt;
  __syncthreads();
  int j = t & 127, half = t >> 7;   // half is wave-uniform
  float acc[16];
  #pragma unroll
  for (int k = 0; k < 16; ++k) acc[k] = 0.f;
  const float* w1row = ws + OW1 + j * 256;
  for (int g = 0; g < 256; g += 4) {
    float4 w1q = *(const float4*)(w1row + g);
    #pragma unroll
    for (int k = 0; k < 16; ++k) {
      float4 mq = *(const float4*)(&Ms[half * 16 + k][g]);  // LDS broadcast
      acc[k] += mq.x * w1q.x + mq.y * w1q.y + mq.z * w1q.z + mq.w * w1q.w;
    }
  }
  #pragma unroll
  for (int k = 0; k < 16; ++k)
    ws[OT + (b * 256 + h0 + half * 16 + k) * 128 + j] = acc[k];
}

// F^2 partial per (batch, 64x64 tile): sum u_h u_h' (P^2 Q + P R R^T)
__global__ __launch_bounds__(256) void k_fred(float* ws) {
  int bid = blockIdx.x;
  int b = bid >> 4, tile = bid & 15;
  int I = (tile >> 2) * 64, J = (tile & 3) * 64;
  int t = threadIdx.x;
  int lane = t & 63, wq = t >> 6;   // wq wave-uniform

  __shared__ float buf[8704];
  __shared__ float uI[64], uJ[64];
  float* PsI = buf;          // [64][32]
  float* MI  = buf + 2048;   // [64][32]
  float* PsJ = buf + 4096;   // [64][36] padded (stride 36 -> conflict-free f4)
  float* MJ  = buf + 6400;   // [64][36]

  if (t < 64)       uI[t]      = ws[OU + b * 256 + I + t];
  else if (t < 128) uJ[t - 64] = ws[OU + b * 256 + J + (t - 64)];

  float racc[16], rtacc[16], qacc[16];
  #pragma unroll
  for (int k = 0; k < 16; ++k) { racc[k] = 0.f; rtacc[k] = 0.f; qacc[k] = 0.f; }

  const float* sb = ws + OS + b * 256;

  // phase A: R[h,h'] and R[h',h], K=256 in 8 chunks of 32
  for (int c = 0; c < 8; ++c) {
    int g0 = c * 32;
    __syncthreads();
    for (int i = t; i < 2048; i += 256) {
      int hl = i >> 5, gl = i & 31;
      float sg = sb[g0 + gl];
      PsI[i]           = ws[OP + (I + hl) * 256 + g0 + gl] * sg;
      MI[i]            = ws[OM + (I + hl) * 256 + g0 + gl];
      PsJ[hl * 36 + gl] = ws[OP + (J + hl) * 256 + g0 + gl] * sg;
      MJ[hl * 36 + gl]  = ws[OM + (J + hl) * 256 + g0 + gl];
    }
    __syncthreads();
    #pragma unroll
    for (int gl = 0; gl < 32; gl += 4) {
      float4 mj = *(const float4*)&MJ[lane * 36 + gl];
      float4 pj = *(const float4*)&PsJ[lane * 36 + gl];
      #pragma unroll
      for (int k = 0; k < 16; ++k) {
        float4 pi = *(const float4*)&PsI[(wq + 4 * k) * 32 + gl];  // broadcast
        float4 mi = *(const float4*)&MI[(wq + 4 * k) * 32 + gl];   // broadcast
        racc[k]  += pi.x * mj.x + pi.y * mj.y + pi.z * mj.z + pi.w * mj.w;
        rtacc[k] += pj.x * mi.x + pj.y * mi.y + pj.z * mi.z + pj.w * mi.w;
      }
    }
  }

  // phase B: Q[h,h'] = sum_j T[h,j] T[h',j], J=128 in 2 chunks of 64
  float* TI = buf;          // [64][64]
  float* TJ = buf + 4096;   // [64][68] padded
  for (int c = 0; c < 2; ++c) {
    int j0 = c * 64;
    __syncthreads();
    for (int i = t; i < 4096; i += 256) {
      int hl = i >> 6, jl = i & 63;
      TI[i]            = ws[OT + (b * 256 + I + hl) * 128 + j0 + jl];
      TJ[hl * 68 + jl] = ws[OT + (b * 256 + J + hl) * 128 + j0 + jl];
    }
    __syncthreads();
    #pragma unroll
    for (int jl = 0; jl < 64; jl += 4) {
      float4 tj = *(const float4*)&TJ[lane * 68 + jl];
      #pragma unroll
      for (int k = 0; k < 16; ++k) {
        float4 ti = *(const float4*)&TI[(wq + 4 * k) * 64 + jl];   // broadcast
        qacc[k] += ti.x * tj.x + ti.y * tj.y + ti.z * tj.z + ti.w * tj.w;
      }
    }
  }

  float part = 0.f;
  #pragma unroll
  for (int k = 0; k < 16; ++k) {
    int h = I + wq + 4 * k, hp = J + lane;
    float Ph = ws[OP + h * 256 + hp];
    float uu = uI[wq + 4 * k] * uJ[lane];
    part += uu * (Ph * Ph * qacc[k] + Ph * racc[k] * rtacc[k]);
  }
  __syncthreads();
  buf[t] = part;
  __syncthreads();
  for (int off = 128; off > 0; off >>= 1) {
    if (t < off) buf[t] += buf[t + off];
    __syncthreads();
  }
  if (t == 0) ws[OF2 + b * 16 + tile] = buf[0];
}

__global__ void k_out(const void* sbin, void* out, const float* ws, const int* flag) {
  int bf = *flag;
  int idx = blockIdx.x * 256 + threadIdx.x;
  if (idx < NB * DD) {
    stout(out, idx, ldin(sbin, NB * DD + idx, bf), bf);   // dev_velocity passthrough
  } else if (idx < 2 * NB * DD) {
    int r = idx - NB * DD;
    int b = r >> 7, i = r & 127;
    float f2 = 0.f;
    #pragma unroll
    for (int k = 0; k < 16; ++k) f2 += ws[OF2 + b * 16 + k];
    float F = sqrtf(fmaxf(2.f * f2, 0.f));
    float denom = (F + 1e-6f) * (ws[OVN + b] + 1e-6f);
    float dev = ldin(sbin, r, bf);
    float val = -ws[OAUN + b * 128 + i] / denom - 0.1f * dev;
    stout(out, idx, val, bf);
  }
}

extern "C" void kernel_launch(void* const* d_in, const int* in_sizes, int n_in,
                              void* d_out, int out_size, void* d_ws, size_t ws_size,
                              hipStream_t stream) {
  float* ws = (float*)d_ws;
  int* flag = (int*)(ws + OFLAG);
  const void* tin  = d_in[0];
  const void* sbin = d_in[1];
  const void* x0in = d_in[2];
  const void* x1in = d_in[3];
  const void* W1in = d_in[4];
  const void* b1in = d_in[5];
  const void* W2in = d_in[6];
  // d_in[7] (b2) is mathematically unused: it cancels in every derivative.

  k_sniff  <<<dim3(1),   dim3(256), 0, stream>>>(sbin, flag);
  k_convert<<<dim3(139), dim3(256), 0, stream>>>(W1in, W2in, b1in, ws, flag);
  k_pm     <<<dim3(256), dim3(256), 0, stream>>>(ws);
  k_batch  <<<dim3(32),  dim3(256), 0, stream>>>(tin, sbin, x0in, x1in, ws, flag);
  k_T      <<<dim3(256), dim3(256), 0, stream>>>(ws);
  k_fred   <<<dim3(512), dim3(256), 0, stream>>>(ws);
  k_out    <<<dim3(32),  dim3(256), 0, stream>>>(sbin, d_out, ws, flag);
}

// Round 2
// 115.885 us; speedup vs baseline: 1.7198x; 1.7198x over previous
//
#include <hip/hip_runtime.h>
#include <hip/hip_bf16.h>

// B=32, D=128, H=256, O=10.
// s = 1-tanh(W1^T x + b1)^2, u = -2 z s, P = W1^T W1 (HxH).
// Rank-10 structure: M = W2 W2^T ->
//   E = P D_s W2 (Hx10/batch), C = W2^T D_s E (10x10), CW = C W2^T (10xH)
//   R[h,h'] = E[h,:]. W2[h',:],  R^T[h,h'] = E[h',:] . W2[h,:]
//   Q[h,h'] = W2[h,:] . CW[:,h']
//   F^2 = 2 sum_{hh'} u_h u_h' (P^2 Q + P R R^T)
//   a_i = -(sum_g s_g W1[i,g] m_g)/((F+1e-6)(||v||+1e-6)), m = W2(W2^T(u o w^2)), w = W1^T v
// Out rows 0..31 = dev_velocity, rows 32..63 = a - 0.1*deviation.

#define NB 32
#define DD 128
#define HH 256

// workspace float offsets
#define OW1   0         // 32768  W1 f32 [d*256+h]
#define OW2   32768     // 2560   W2 f32 [h*10+o]
#define OB1   35328     // 256
#define OP    35584     // 65536  P [h*256+g]
#define OS    101120    // 32x256
#define OU    109312    // 32x256
#define OE    117504    // 32x256x12: [0..9]=E, [10]=u, [11]=0
#define OCW   215808    // 32x10x256: CW[b][o][h']
#define OAUN  297728    // 32x128
#define OVN   301824    // 32
#define OF2   301856    // 32x16

__device__ __forceinline__ float ldin(const void* p, int i, int bf) {
  if (bf) return __bfloat162float(((const __hip_bfloat16*)p)[i]);
  return ((const float*)p)[i];
}
__device__ __forceinline__ void stout(void* p, int i, float v, int bf) {
  if (bf) ((__hip_bfloat16*)p)[i] = __float2bfloat16(v);
  else    ((float*)p)[i] = v;
}

// Per-block dtype sniff: view first 256 half-words of state_batch as bf16.
// If storage is fp32, the low halves of the 128 fp32 words have random
// exponents -> some |v|>1000 w.p. 1-0.54^128. True bf16 N(0,1) stays small.
__device__ __forceinline__ int blocksniff(const void* sb, int* sh) {
  if (threadIdx.x == 0) *sh = 0;
  __syncthreads();
  float v = fabsf(__bfloat162float(((const __hip_bfloat16*)sb)[threadIdx.x & 255]));
  if (!(v < 1000.0f)) atomicOr(sh, 1);
  __syncthreads();
  return (*sh == 0) ? 1 : 0;
}

__global__ __launch_bounds__(256) void k_convert(const void* W1, const void* W2,
                                                 const void* b1, const void* sb,
                                                 float* ws) {
  __shared__ int sh;
  int bf = blocksniff(sb, &sh);
  int i = blockIdx.x * 256 + threadIdx.x;
  if (i < 32768)       ws[OW1 + i] = ldin(W1, i, bf);
  else if (i < 35328)  ws[OW2 + (i - 32768)] = ldin(W2, i - 32768, bf);
  else if (i < 35584)  ws[OB1 + (i - 35328)] = ldin(b1, i - 35328, bf);
}

// P[h,t] = sum_d W1[d,h] W1[d,t]
__global__ __launch_bounds__(256) void k_P(float* ws) {
  __shared__ __align__(16) float colh[128];
  int h = blockIdx.x, t = threadIdx.x;
  if (t < 128) colh[t] = ws[OW1 + t * 256 + h];
  __syncthreads();
  float pacc = 0.f;
  for (int d = 0; d < 128; d += 4) {
    float4 c4 = *(const float4*)&colh[d];
    pacc += c4.x * ws[OW1 + (d + 0) * 256 + t];
    pacc += c4.y * ws[OW1 + (d + 1) * 256 + t];
    pacc += c4.z * ws[OW1 + (d + 2) * 256 + t];
    pacc += c4.w * ws[OW1 + (d + 3) * 256 + t];
  }
  ws[OP + h * 256 + t] = pacc;
}

// per batch: s, u, ||v||, a_un (rank-10 m)
__global__ __launch_bounds__(256) void k_batch(const void* tin, const void* sbin,
                                               const void* x0in, const void* x1in,
                                               float* ws) {
  __shared__ int sh;
  __shared__ float xs[128], vs[128], tmp[256], sm[256], ys[10];
  int bf = blocksniff(sbin, &sh);
  int b = blockIdx.x, t = threadIdx.x;
  float tt = ldin(tin, 0, bf);
  float window = 4.f * tt * (1.f - tt);
  if (t < 128) {
    float dev = ldin(sbin, b * 128 + t, bf);
    float v   = ldin(sbin, (NB + b) * 128 + t, bf);
    float x0v = ldin(x0in, b * 128 + t, bf);
    float x1v = ldin(x1in, b * 128 + t, bf);
    xs[t] = x0v + tt * (x1v - x0v) + window * dev;
    vs[t] = v;
  }
  __syncthreads();
  if (t == 0) {
    float sum = 0.f;
    for (int i = 0; i < 128; ++i) sum += vs[i] * vs[i];
    ws[OVN + b] = sqrtf(sum);
  }
  float hacc = ws[OB1 + t], wacc = 0.f;
  for (int d = 0; d < 128; ++d) {
    float w1 = ws[OW1 + d * 256 + t];   // coalesced over t
    hacc += w1 * xs[d];
    wacc += w1 * vs[d];
  }
  float z  = tanhf(hacc);
  float sg = 1.f - z * z;
  float ug = -2.f * z * sg;
  ws[OS + b * 256 + t] = sg;
  ws[OU + b * 256 + t] = ug;
  tmp[t] = ug * wacc * wacc;           // c_h
  __syncthreads();
  if (t < 10) {                        // y_o = sum_h W2[h,o] c_h
    float y = 0.f;
    for (int h = 0; h < 256; ++h) y += ws[OW2 + h * 10 + t] * tmp[h];
    ys[t] = y;
  }
  __syncthreads();
  float mg = 0.f;                      // m_t = sum_o W2[t,o] y_o
  #pragma unroll
  for (int o = 0; o < 10; ++o) mg += ws[OW2 + t * 10 + o] * ys[o];
  sm[t] = sg * mg;
  __syncthreads();
  if (t < 128) {
    float a = 0.f;
    for (int g = 0; g < 256; ++g) a += ws[OW1 + t * 256 + g] * sm[g];
    ws[OAUN + b * 128 + t] = a;
  }
}

// E[h,o] = sum_g P[h,g] (s_g W2[g,o]); grid (4 row-quarters, 32 batches)
__global__ __launch_bounds__(256) void k_E(float* ws) {
  int b = blockIdx.y, q = blockIdx.x, t = threadIdx.x;
  int hl = t & 63, kp = t >> 6;
  __shared__ __align__(16) float sw2[256 * 12];
  __shared__ float ep[4 * 64 * 10];
  for (int i = t; i < 2560; i += 256) {
    int g = i / 10, o = i % 10;
    sw2[g * 12 + o] = ws[OS + b * 256 + g] * ws[OW2 + i];
  }
  __syncthreads();
  float acc[10];
  #pragma unroll
  for (int o = 0; o < 10; ++o) acc[o] = 0.f;
  int h = q * 64 + hl;
  const float* prow = ws + OP + h * 256 + kp * 64;
  for (int gg = 0; gg < 64; gg += 4) {
    float4 p4 = *(const float4*)(prow + gg);
    float pj[4] = {p4.x, p4.y, p4.z, p4.w};
    #pragma unroll
    for (int j = 0; j < 4; ++j) {
      int base = (kp * 64 + gg + j) * 12;
      float4 a0 = *(const float4*)&sw2[base];
      float4 a1 = *(const float4*)&sw2[base + 4];
      float2 a2 = *(const float2*)&sw2[base + 8];
      float p = pj[j];
      acc[0] += p * a0.x; acc[1] += p * a0.y; acc[2] += p * a0.z; acc[3] += p * a0.w;
      acc[4] += p * a1.x; acc[5] += p * a1.y; acc[6] += p * a1.z; acc[7] += p * a1.w;
      acc[8] += p * a2.x; acc[9] += p * a2.y;
    }
  }
  #pragma unroll
  for (int o = 0; o < 10; ++o) ep[kp * 640 + hl * 10 + o] = acc[o];
  __syncthreads();
  for (int i = t; i < 640; i += 256) {
    float e = ep[i] + ep[640 + i] + ep[1280 + i] + ep[1920 + i];
    int h2 = i / 10, o = i % 10;
    ws[OE + (b * 256 + q * 64 + h2) * 12 + o] = e;
  }
  if (t < 64) {
    ws[OE + (b * 256 + q * 64 + t) * 12 + 10] = ws[OU + b * 256 + q * 64 + t];
    ws[OE + (b * 256 + q * 64 + t) * 12 + 11] = 0.f;
  }
}

// C = W2^T D_s E (10x10), CW[o,h'] = sum_p C[o,p] W2[h',p]
__global__ __launch_bounds__(256) void k_CW(float* ws) {
  int b = blockIdx.x, t = threadIdx.x;
  __shared__ float eL[3072], w2L[2560], sL[256], cL[100];
  for (int i = t; i < 3072; i += 256) eL[i] = ws[OE + b * 3072 + i];
  for (int i = t; i < 2560; i += 256) w2L[i] = ws[OW2 + i];
  sL[t] = ws[OS + b * 256 + t];
  __syncthreads();
  if (t < 100) {
    int o = t / 10, p = t % 10;
    float c = 0.f;
    for (int g = 0; g < 256; ++g) c += w2L[g * 10 + o] * sL[g] * eL[g * 12 + p];
    cL[t] = c;
  }
  __syncthreads();
  float w2r[10];
  #pragma unroll
  for (int p = 0; p < 10; ++p) w2r[p] = w2L[t * 10 + p];
  #pragma unroll
  for (int o = 0; o < 10; ++o) {
    float cw = 0.f;
    #pragma unroll
    for (int p = 0; p < 10; ++p) cw += cL[o * 10 + p] * w2r[p];
    ws[OCW + b * 2560 + o * 256 + t] = cw;
  }
}

// F^2 partial per (batch, 16-row strip): thread t = column h'
__global__ __launch_bounds__(256) void k_f2(float* ws) {
  int b = blockIdx.y, strip = blockIdx.x, t = threadIdx.x;
  int h0 = strip * 16;
  __shared__ __align__(16) float rec[16 * 24];  // [0..9]=E,[10]=u,[11]=pad,[12..21]=W2row,[22..23]=pad
  __shared__ float red[256];
  float uT = ws[OU + b * 256 + t];
  float w2r[10], cwr[10], er[10];
  #pragma unroll
  for (int o = 0; o < 10; ++o) w2r[o] = ws[OW2 + t * 10 + o];
  #pragma unroll
  for (int o = 0; o < 10; ++o) cwr[o] = ws[OCW + b * 2560 + o * 256 + t];
  {
    const float* ep = ws + OE + (b * 256 + t) * 12;
    float4 e0 = *(const float4*)ep;
    float4 e1 = *(const float4*)(ep + 4);
    float2 e2 = *(const float2*)(ep + 8);
    er[0]=e0.x; er[1]=e0.y; er[2]=e0.z; er[3]=e0.w;
    er[4]=e1.x; er[5]=e1.y; er[6]=e1.z; er[7]=e1.w;
    er[8]=e2.x; er[9]=e2.y;
  }
  for (int i = t; i < 384; i += 256) {
    int r = i / 24, c = i % 24, h = h0 + r;
    float v;
    if (c < 12)      v = ws[OE + (b * 256 + h) * 12 + c];
    else if (c < 22) v = ws[OW2 + h * 10 + (c - 12)];
    else             v = 0.f;
    rec[i] = v;
  }
  __syncthreads();
  float acc = 0.f;
  #pragma unroll
  for (int hl = 0; hl < 16; ++hl) {
    float Pht = ws[OP + (h0 + hl) * 256 + t];
    const float* rp = &rec[hl * 24];
    float4 E0 = *(const float4*)rp;
    float4 E1 = *(const float4*)(rp + 4);
    float4 E2 = *(const float4*)(rp + 8);    // E8,E9,u,pad
    float4 W0 = *(const float4*)(rp + 12);
    float4 W1v = *(const float4*)(rp + 16);
    float2 W2v = *(const float2*)(rp + 20);  // W28,W29
    float R = E0.x*w2r[0] + E0.y*w2r[1] + E0.z*w2r[2] + E0.w*w2r[3]
            + E1.x*w2r[4] + E1.y*w2r[5] + E1.z*w2r[6] + E1.w*w2r[7]
            + E2.x*w2r[8] + E2.y*w2r[9];
    float Rt = W0.x*er[0] + W0.y*er[1] + W0.z*er[2] + W0.w*er[3]
             + W1v.x*er[4] + W1v.y*er[5] + W1v.z*er[6] + W1v.w*er[7]
             + W2v.x*er[8] + W2v.y*er[9];
    float Qd = W0.x*cwr[0] + W0.y*cwr[1] + W0.z*cwr[2] + W0.w*cwr[3]
             + W1v.x*cwr[4] + W1v.y*cwr[5] + W1v.z*cwr[6] + W1v.w*cwr[7]
             + W2v.x*cwr[8] + W2v.y*cwr[9];
    float uh = E2.z;
    acc += uh * Pht * (Pht * Qd + R * Rt);
  }
  acc *= uT;
  red[t] = acc;
  __syncthreads();
  for (int off = 128; off > 0; off >>= 1) {
    if (t < off) red[t] += red[t + off];
    __syncthreads();
  }
  if (t == 0) ws[OF2 + b * 16 + strip] = red[0];
}

__global__ __launch_bounds__(256) void k_out(const void* sbin, void* out, const float* ws) {
  __shared__ int sh;
  int bf = blocksniff(sbin, &sh);
  int idx = blockIdx.x * 256 + threadIdx.x;
  if (idx < NB * DD) {
    stout(out, idx, ldin(sbin, NB * DD + idx, bf), bf);   // dev_velocity passthrough
  } else if (idx < 2 * NB * DD) {
    int r = idx - NB * DD;
    int b = r >> 7, i = r & 127;
    float f2 = 0.f;
    #pragma unroll
    for (int k = 0; k < 16; ++k) f2 += ws[OF2 + b * 16 + k];
    float F = sqrtf(fmaxf(2.f * f2, 0.f));
    float denom = (F + 1e-6f) * (ws[OVN + b] + 1e-6f);
    float dev = ldin(sbin, r, bf);
    float val = -ws[OAUN + b * 128 + i] / denom - 0.1f * dev;
    stout(out, idx, val, bf);
  }
}

extern "C" void kernel_launch(void* const* d_in, const int* in_sizes, int n_in,
                              void* d_out, int out_size, void* d_ws, size_t ws_size,
                              hipStream_t stream) {
  float* ws = (float*)d_ws;
  const void* tin  = d_in[0];
  const void* sbin = d_in[1];
  const void* x0in = d_in[2];
  const void* x1in = d_in[3];
  const void* W1in = d_in[4];
  const void* b1in = d_in[5];
  const void* W2in = d_in[6];
  // d_in[7] (b2) cancels in every derivative.

  k_convert<<<dim3(139),        dim3(256), 0, stream>>>(W1in, W2in, b1in, sbin, ws);
  k_P      <<<dim3(256),        dim3(256), 0, stream>>>(ws);
  k_batch  <<<dim3(32),         dim3(256), 0, stream>>>(tin, sbin, x0in, x1in, ws);
  k_E      <<<dim3(4, 32),      dim3(256), 0, stream>>>(ws);
  k_CW     <<<dim3(32),         dim3(256), 0, stream>>>(ws);
  k_f2     <<<dim3(16, 32),     dim3(256), 0, stream>>>(ws);
  k_out    <<<dim3(32),         dim3(256), 0, stream>>>(sbin, d_out, ws);
}

// Round 3
// 112.533 us; speedup vs baseline: 1.7710x; 1.0298x over previous
//
#include <hip/hip_runtime.h>
#include <hip/hip_bf16.h>

// B=32, D=128, H=256, O=10.
// s = 1-tanh(W1^T x + b1)^2, u = -2 z s, P = W1^T W1 (HxH).
// Rank-10 structure (M = W2 W2^T):
//   E = P D_s W2 = W1^T (W1 (D_s W2))   (factored; no P needed)
//   C = W2^T D_s E (10x10), CW = C W2^T (10xH)
//   R[h,h'] = E[h,:].W2[h',:], R^T[h,h'] = W2[h,:].E[h',:], Q[h,h'] = W2[h,:].CW[:,h']
//   F^2 = 2 sum_{hh'} u_h u_h' (P^2 o Q + P o R o R^T)
//   a_i = -(sum_g s_g W1[i,g] m_g)/((F+1e-6)(||v||+1e-6)), m = W2(W2^T(u o w^2)), w = W1^T v
// Out rows 0..31 = dev_velocity, rows 32..63 = a - 0.1*deviation.
// Two kernels: K1 = P rows (256 blk) + per-batch prep/E/C/CW (32 blk); K2 = F^2 + output.

#define NB 32

// workspace float offsets
#define OP    0        // 65536   P [h*256+g]
#define OE    65536    // 32*256*12: [0..9]=E, [10]=u, [11]=0
#define OCW   163840   // 32*10*256: CW[b][o][h']
#define OAUN  245760   // 32*128
#define OVN   249856   // 32

template<int BF> __device__ __forceinline__ float ld(const void* p, int i) {
  if constexpr (BF) return __bfloat162float(((const __hip_bfloat16*)p)[i]);
  else return ((const float*)p)[i];
}
template<int BF> __device__ __forceinline__ void st(void* p, int i, float v) {
  if constexpr (BF) ((__hip_bfloat16*)p)[i] = __float2bfloat16(v);
  else ((float*)p)[i] = v;
}

// dtype sniff: view first 256 half-words of state_batch as bf16. fp32 storage
// puts random-exponent garbage in the low halves -> some |v|>1000 w.p. ~1.
__device__ __forceinline__ int blocksniff(const void* sb, int* sh) {
  if (threadIdx.x == 0) *sh = 0;
  __syncthreads();
  float v = fabsf(__bfloat162float(((const __hip_bfloat16*)sb)[threadIdx.x & 255]));
  if (!(v < 1000.0f)) atomicOr(sh, 1);
  __syncthreads();
  return (*sh == 0) ? 1 : 0;
}

// LDS carve (floats) for K1 batch path
#define LXS   0      // 128
#define LVS   128    // 128
#define LW2   256    // 2560
#define LTMP  2816   // 256
#define LYS   3072   // 16
#define LSMV  3088   // 256
#define LSAR  3344   // 256
#define LF1   3600   // 128*12
#define LEL   5136   // 256*12
#define LCL   8208   // 112
#define LSW2  8320   // 256*12
#define LTOT  11392

template<int BF>
__device__ void k1_body(const void* tin, const void* sbin, const void* x0in,
                        const void* x1in, const void* W1in, const void* b1in,
                        const void* W2in, float* ws, float* sm) {
  int bid = blockIdx.x, t = threadIdx.x;
  if (bid < 256) {
    // P row bid
    float* colh = sm;            // 128
    if (t < 128) colh[t] = ld<BF>(W1in, t * 256 + bid);
    __syncthreads();
    float pacc = 0.f;
    for (int d = 0; d < 128; d += 4) {
      float4 c4 = *(const float4*)&colh[d];
      pacc += c4.x * ld<BF>(W1in, (d + 0) * 256 + t);
      pacc += c4.y * ld<BF>(W1in, (d + 1) * 256 + t);
      pacc += c4.z * ld<BF>(W1in, (d + 2) * 256 + t);
      pacc += c4.w * ld<BF>(W1in, (d + 3) * 256 + t);
    }
    ws[OP + bid * 256 + t] = pacc;
    return;
  }
  int b = bid - 256;
  float tt = ld<BF>(tin, 0);
  float window = 4.f * tt * (1.f - tt);
  if (t < 128) {
    float dev = ld<BF>(sbin, b * 128 + t);
    float v   = ld<BF>(sbin, (NB + b) * 128 + t);
    float x0v = ld<BF>(x0in, b * 128 + t);
    float x1v = ld<BF>(x1in, b * 128 + t);
    sm[LXS + t] = x0v + tt * (x1v - x0v) + window * dev;
    sm[LVS + t] = v;
  }
  for (int i = t; i < 2560; i += 256) sm[LW2 + i] = ld<BF>(W2in, i);
  __syncthreads();
  // h, w projections
  float hacc = ld<BF>(b1in, t), wacc = 0.f;
  for (int d = 0; d < 128; ++d) {
    float w1v = ld<BF>(W1in, d * 256 + t);   // coalesced over t
    hacc += w1v * sm[LXS + d];
    wacc += w1v * sm[LVS + d];
  }
  float z  = tanhf(hacc);
  float sg = 1.f - z * z;
  float ug = -2.f * z * sg;
  sm[LSAR + t] = sg;
  // ||v|| tree
  sm[LTMP + t] = (t < 128) ? sm[LVS + t] * sm[LVS + t] : 0.f;
  __syncthreads();
  for (int off = 128; off > 0; off >>= 1) {
    if (t < off) sm[LTMP + t] += sm[LTMP + t + off];
    __syncthreads();
  }
  if (t == 0) ws[OVN + b] = sqrtf(sm[LTMP]);
  __syncthreads();
  // c_h = u_h w_h^2 -> y = W2^T c -> m = W2 y -> smv = s o m
  sm[LTMP + t] = ug * wacc * wacc;
  __syncthreads();
  if (t < 10) {
    float y = 0.f;
    for (int h = 0; h < 256; ++h) y += sm[LW2 + h * 10 + t] * sm[LTMP + h];
    sm[LYS + t] = y;
  }
  __syncthreads();
  {
    float mg = 0.f;
    #pragma unroll
    for (int o = 0; o < 10; ++o) mg += sm[LW2 + t * 10 + o] * sm[LYS + o];
    sm[LSMV + t] = sg * mg;
  }
  // sw2[g,o] = s_g W2[g,o], stride-12 padded
  for (int i = t; i < 3072; i += 256) {
    int g = i / 12, c = i % 12;
    sm[LSW2 + i] = (c < 10) ? sm[LSAR + g] * sm[LW2 + g * 10 + c] : 0.f;
  }
  __syncthreads();
  // a_un[i] = sum_g W1[i,g] smv[g]  (t<128)
  if (t < 128) {
    float a = 0.f;
    for (int g = 0; g < 256; ++g) a += ld<BF>(W1in, t * 256 + g) * sm[LSMV + g];
    ws[OAUN + b * 128 + t] = a;
  }
  // F1[d,o] = sum_g W1[d,g] sw2[g,o]  (t<128 computes row t)
  if (t < 128) {
    float fa[10];
    #pragma unroll
    for (int o = 0; o < 10; ++o) fa[o] = 0.f;
    for (int g = 0; g < 256; ++g) {
      float w1v = ld<BF>(W1in, t * 256 + g);
      const float* sp = &sm[LSW2 + g * 12];
      float4 a0 = *(const float4*)sp;
      float4 a1 = *(const float4*)(sp + 4);
      float2 a2 = *(const float2*)(sp + 8);
      fa[0] += w1v * a0.x; fa[1] += w1v * a0.y; fa[2] += w1v * a0.z; fa[3] += w1v * a0.w;
      fa[4] += w1v * a1.x; fa[5] += w1v * a1.y; fa[6] += w1v * a1.z; fa[7] += w1v * a1.w;
      fa[8] += w1v * a2.x; fa[9] += w1v * a2.y;
    }
    #pragma unroll
    for (int o = 0; o < 10; ++o) sm[LF1 + t * 12 + o] = fa[o];
    sm[LF1 + t * 12 + 10] = 0.f; sm[LF1 + t * 12 + 11] = 0.f;
  }
  __syncthreads();
  // E[t,o] = sum_d W1[d,t] F1[d,o]
  float er[10];
  #pragma unroll
  for (int o = 0; o < 10; ++o) er[o] = 0.f;
  for (int d = 0; d < 128; ++d) {
    float w1v = ld<BF>(W1in, d * 256 + t);   // coalesced
    const float* fp = &sm[LF1 + d * 12];
    float4 a0 = *(const float4*)fp;
    float4 a1 = *(const float4*)(fp + 4);
    float2 a2 = *(const float2*)(fp + 8);
    er[0] += w1v * a0.x; er[1] += w1v * a0.y; er[2] += w1v * a0.z; er[3] += w1v * a0.w;
    er[4] += w1v * a1.x; er[5] += w1v * a1.y; er[6] += w1v * a1.z; er[7] += w1v * a1.w;
    er[8] += w1v * a2.x; er[9] += w1v * a2.y;
  }
  #pragma unroll
  for (int o = 0; o < 10; ++o) sm[LEL + t * 12 + o] = er[o];
  // packed global write: E[0..9], u, 0
  {
    float* gp = ws + OE + (b * 256 + t) * 12;
    *(float4*)gp       = make_float4(er[0], er[1], er[2], er[3]);
    *(float4*)(gp + 4) = make_float4(er[4], er[5], er[6], er[7]);
    *(float4*)(gp + 8) = make_float4(er[8], er[9], ug, 0.f);
  }
  __syncthreads();
  // C[o,p] = sum_g W2[g,o] s_g E[g,p]
  if (t < 100) {
    int o = t / 10, p = t % 10;
    float c = 0.f;
    for (int g = 0; g < 256; ++g)
      c += sm[LW2 + g * 10 + o] * sm[LSAR + g] * sm[LEL + g * 12 + p];
    sm[LCL + t] = c;
  }
  __syncthreads();
  // CW[o,t] = sum_p C[o,p] W2[t,p]
  {
    float w2r[10];
    #pragma unroll
    for (int p = 0; p < 10; ++p) w2r[p] = sm[LW2 + t * 10 + p];
    #pragma unroll
    for (int o = 0; o < 10; ++o) {
      float cw = 0.f;
      #pragma unroll
      for (int p = 0; p < 10; ++p) cw += sm[LCL + o * 10 + p] * w2r[p];
      ws[OCW + b * 2560 + o * 256 + t] = cw;
    }
  }
}

__global__ __launch_bounds__(256) void K1(const void* tin, const void* sbin,
                                          const void* x0in, const void* x1in,
                                          const void* W1in, const void* b1in,
                                          const void* W2in, float* ws) {
  __shared__ int sh;
  __shared__ __align__(16) float sm[LTOT];
  int bf = blocksniff(sbin, &sh);
  if (bf) k1_body<1>(tin, sbin, x0in, x1in, W1in, b1in, W2in, ws, sm);
  else    k1_body<0>(tin, sbin, x0in, x1in, W1in, b1in, W2in, ws, sm);
}

template<int BF>
__device__ void k2_body(const void* sbin, const void* W2in, void* out, float* ws,
                        float* rec, float* w2h, float* red) {
  int b = blockIdx.x, t = threadIdx.x;
  int w = t >> 6;
  for (int i = t; i < 3072; i += 256) rec[i] = ws[OE + b * 3072 + i];
  for (int i = t; i < 3072; i += 256) {
    int r = i / 12, c = i % 12;
    w2h[i] = (c < 10) ? ld<BF>(W2in, r * 10 + c) : 0.f;
  }
  __syncthreads();
  float cwr[10], er[10], w2r[10];
  #pragma unroll
  for (int o = 0; o < 10; ++o) cwr[o] = ws[OCW + b * 2560 + o * 256 + t];
  #pragma unroll
  for (int o = 0; o < 10; ++o) er[o] = rec[t * 12 + o];
  float uT = rec[t * 12 + 10];
  #pragma unroll
  for (int o = 0; o < 10; ++o) w2r[o] = w2h[t * 12 + o];
  float acc = 0.f;
  for (int i = 0; i < 64; ++i) {
    int h = w * 64 + i;
    float Ph = ws[OP + h * 256 + t];          // coalesced, L2
    const float* rp = &rec[h * 12];
    float4 E0 = *(const float4*)rp;
    float4 E1 = *(const float4*)(rp + 4);
    float4 E2 = *(const float4*)(rp + 8);     // E8,E9,u,0
    const float* wp = &w2h[h * 12];
    float4 W0 = *(const float4*)wp;
    float4 W1v = *(const float4*)(wp + 4);
    float4 W2v = *(const float4*)(wp + 8);    // W8,W9,0,0
    float R = E0.x*w2r[0] + E0.y*w2r[1] + E0.z*w2r[2] + E0.w*w2r[3]
            + E1.x*w2r[4] + E1.y*w2r[5] + E1.z*w2r[6] + E1.w*w2r[7]
            + E2.x*w2r[8] + E2.y*w2r[9];
    float Rt = W0.x*er[0] + W0.y*er[1] + W0.z*er[2] + W0.w*er[3]
             + W1v.x*er[4] + W1v.y*er[5] + W1v.z*er[6] + W1v.w*er[7]
             + W2v.x*er[8] + W2v.y*er[9];
    float Qd = W0.x*cwr[0] + W0.y*cwr[1] + W0.z*cwr[2] + W0.w*cwr[3]
             + W1v.x*cwr[4] + W1v.y*cwr[5] + W1v.z*cwr[6] + W1v.w*cwr[7]
             + W2v.x*cwr[8] + W2v.y*cwr[9];
    acc += E2.z * Ph * (Ph * Qd + R * Rt);
  }
  red[t] = acc * uT;
  __syncthreads();
  for (int off = 128; off > 0; off >>= 1) {
    if (t < off) red[t] += red[t + off];
    __syncthreads();
  }
  float F = sqrtf(fmaxf(2.f * red[0], 0.f));
  float denom = (F + 1e-6f) * (ws[OVN + b] + 1e-6f);
  if (t < 128) {
    st<BF>(out, b * 128 + t, ld<BF>(sbin, (NB + b) * 128 + t));   // dev_velocity
    float dev = ld<BF>(sbin, b * 128 + t);
    float val = -ws[OAUN + b * 128 + t] / denom - 0.1f * dev;
    st<BF>(out, (NB + b) * 128 + t, val);
  }
}

__global__ __launch_bounds__(256) void K2(const void* sbin, const void* W2in,
                                          void* out, float* ws) {
  __shared__ int sh;
  __shared__ __align__(16) float rec[3072];
  __shared__ __align__(16) float w2h[3072];
  __shared__ float red[256];
  int bf = blocksniff(sbin, &sh);
  if (bf) k2_body<1>(sbin, W2in, out, ws, rec, w2h, red);
  else    k2_body<0>(sbin, W2in, out, ws, rec, w2h, red);
}

extern "C" void kernel_launch(void* const* d_in, const int* in_sizes, int n_in,
                              void* d_out, int out_size, void* d_ws, size_t ws_size,
                              hipStream_t stream) {
  float* ws = (float*)d_ws;
  const void* tin  = d_in[0];
  const void* sbin = d_in[1];
  const void* x0in = d_in[2];
  const void* x1in = d_in[3];
  const void* W1in = d_in[4];
  const void* b1in = d_in[5];
  const void* W2in = d_in[6];
  // d_in[7] (b2) cancels in every derivative.

  K1<<<dim3(288), dim3(256), 0, stream>>>(tin, sbin, x0in, x1in, W1in, b1in, W2in, ws);
  K2<<<dim3(32),  dim3(256), 0, stream>>>(sbin, W2in, d_out, ws);
}